// Round 11
// baseline (366.204 us; speedup 1.0000x reference)
//
#include <hip/hip_runtime.h>
#include <hip/hip_bf16.h>

typedef __attribute__((ext_vector_type(8))) short bf16x8;
typedef __attribute__((ext_vector_type(4))) float f32x4;

__device__ __forceinline__ short f2bf(float f) {
    union { float f; unsigned u; } v; v.f = f;
    unsigned r = (v.u + 0x7FFFu + ((v.u >> 16) & 1u)) >> 16;
    return (short)r;
}
__device__ __forceinline__ float bf2f(short s) {
    union { unsigned u; float f; } v; v.u = ((unsigned)(unsigned short)s) << 16;
    return v.f;
}
__device__ __forceinline__ void gll16(const void* g, void* l) {
    __builtin_amdgcn_global_load_lds(
        (const __attribute__((address_space(1))) unsigned int*)g,
        (__attribute__((address_space(3))) unsigned int*)l, 16, 0, 0);
}

// Q projection pre-scaled by 0.125 * log2(e): softmax runs in exp2 domain.
#define QSCALE 0.18033688011112042f

// ---------------------------------------------------------------------------
// Fused prep: [0,6144) f32->bf16 cvt of q,k,v ; [6144,10240) weight transpose
// +cvt ; [10240,11264) mask bit-pack.
__global__ __launch_bounds__(256) void k_prep(
    const float* __restrict__ qin, const float* __restrict__ kin, const float* __restrict__ vin,
    short* __restrict__ qbf, short* __restrict__ kbf, short* __restrict__ vbf,
    const float* __restrict__ Wq, const float* __restrict__ Wk,
    const float* __restrict__ Wv, const float* __restrict__ Wo,
    short* __restrict__ WqT, short* __restrict__ WkT,
    short* __restrict__ WvT, short* __restrict__ WoT,
    const int* __restrict__ mask, unsigned* __restrict__ mb)
{
    __shared__ int sm[8192];
    const int bid = blockIdx.x, tid = threadIdx.x;
    if (bid < 6144) {
        const float* in = bid < 2048 ? qin : (bid < 4096 ? kin : vin);
        short* out = bid < 2048 ? qbf : (bid < 4096 ? kbf : vbf);
        const long i = ((long)(bid & 2047) * 256 + tid) * 8;
        float4 f0 = *reinterpret_cast<const float4*>(&in[i]);
        float4 f1 = *reinterpret_cast<const float4*>(&in[i + 4]);
        bf16x8 v;
        v[0] = f2bf(f0.x); v[1] = f2bf(f0.y); v[2] = f2bf(f0.z); v[3] = f2bf(f0.w);
        v[4] = f2bf(f1.x); v[5] = f2bf(f1.y); v[6] = f2bf(f1.z); v[7] = f2bf(f1.w);
        *reinterpret_cast<bf16x8*>(&out[i]) = v;
    } else if (bid < 10240) {
        const int t2 = bid - 6144, which = t2 >> 10, local = t2 & 1023;
        const float* W = which == 0 ? Wq : (which == 1 ? Wk : (which == 2 ? Wv : Wo));
        short* WT = which == 0 ? WqT : (which == 1 ? WkT : (which == 2 ? WvT : WoT));
        float (*t)[33] = reinterpret_cast<float(*)[33]>(sm);
        const int rb = (local >> 5) * 32, cb = (local & 31) * 32;
        const int tr = tid >> 3, tc = (tid & 7) * 4;
        const float4 v = *reinterpret_cast<const float4*>(&W[(long)(rb + tr) * 1024 + cb + tc]);
        t[tr][tc + 0] = v.x; t[tr][tc + 1] = v.y; t[tr][tc + 2] = v.z; t[tr][tc + 3] = v.w;
        __syncthreads();
        short4 o;
        o.x = f2bf(t[tc + 0][tr]); o.y = f2bf(t[tc + 1][tr]);
        o.z = f2bf(t[tc + 2][tr]); o.w = f2bf(t[tc + 3][tr]);
        *reinterpret_cast<short4*>(&WT[(long)(cb + tr) * 1024 + rb + tc]) = o;
    } else {
        const long base = (long)(bid - 10240) * 8192;
#pragma unroll
        for (int i = 0; i < 8; ++i)
            *reinterpret_cast<int4*>(&sm[i * 1024 + tid * 4]) =
                *reinterpret_cast<const int4*>(&mask[base + i * 1024 + tid * 4]);
        __syncthreads();
        unsigned wv = 0;
#pragma unroll
        for (int j = 0; j < 32; ++j) wv |= (sm[tid * 32 + j] != 0 ? 1u : 0u) << j;
        mb[base / 32 + tid] = wv;
    }
}

// ---------------------------------------------------------------------------
// Fused QKV projection GEMM (z = 0:Q, 1:K, 2:V). 128x128 tile, BK=64, gll.
__global__ __launch_bounds__(256) void k_gemm_qkv(
    const short* __restrict__ A0, const short* __restrict__ A1, const short* __restrict__ A2,
    const short* __restrict__ B0, const short* __restrict__ B1, const short* __restrict__ B2,
    const float* __restrict__ b0, const float* __restrict__ b1, const float* __restrict__ b2,
    short* __restrict__ o0, short* __restrict__ o1, short* __restrict__ o2)
{
    __shared__ short As[128 * 64];
    __shared__ short Bs[128 * 64];
    const int z = blockIdx.z;
    const short* A = z == 0 ? A0 : (z == 1 ? A1 : A2);
    const short* BT = z == 0 ? B0 : (z == 1 ? B1 : B2);
    const float* bias = z == 0 ? b0 : (z == 1 ? b1 : b2);
    short* outp = z == 0 ? o0 : (z == 1 ? o1 : o2);
    const float scale = z == 0 ? QSCALE : 1.0f;

    const int tid = threadIdx.x, w = tid >> 6, lane = tid & 63;
    const int lr = lane & 15, lg = lane >> 4;
    const int rowbase = blockIdx.y * 128, colbase = blockIdx.x * 128;
    const int wr = (w >> 1) * 64, wc = (w & 1) * 64;
    const int srow = lane >> 3, sc_ = (lane & 7) ^ srow;

    f32x4 acc[4][4] = {};

    for (int kb = 0; kb < 1024; kb += 64) {
#pragma unroll
        for (int ii = 0; ii < 4; ++ii) {
            const int rl = w * 32 + ii * 8 + srow;
            gll16(A + (long)(rowbase + rl) * 1024 + kb + sc_ * 8, &As[(w * 32 + ii * 8) * 64]);
            gll16(BT + (long)(colbase + rl) * 1024 + kb + sc_ * 8, &Bs[(w * 32 + ii * 8) * 64]);
        }
        __syncthreads();
#pragma unroll
        for (int ks = 0; ks < 2; ++ks) {
            bf16x8 a[4], bq[4];
#pragma unroll
            for (int m = 0; m < 4; ++m) {
                const int r = wr + m * 16 + lr;
                a[m] = *reinterpret_cast<const bf16x8*>(&As[r * 64 + (((ks * 4 + lg) ^ (r & 7)) << 3)]);
            }
#pragma unroll
            for (int n = 0; n < 4; ++n) {
                const int r = wc + n * 16 + lr;
                bq[n] = *reinterpret_cast<const bf16x8*>(&Bs[r * 64 + (((ks * 4 + lg) ^ (r & 7)) << 3)]);
            }
#pragma unroll
            for (int m = 0; m < 4; ++m)
#pragma unroll
                for (int n = 0; n < 4; ++n)
                    acc[m][n] = __builtin_amdgcn_mfma_f32_16x16x32_bf16(a[m], bq[n], acc[m][n], 0, 0, 0);
        }
        __syncthreads();
    }

#pragma unroll
    for (int m = 0; m < 4; ++m) {
#pragma unroll
        for (int n = 0; n < 4; ++n) {
            const int C = colbase + wc + n * 16 + lr;
            const float bv = bias[C];
            if (z != 2) {
#pragma unroll
                for (int rr = 0; rr < 4; ++rr) {
                    const int R = rowbase + wr + m * 16 + lg * 4 + rr;
                    const float val = (acc[m][n][rr] + bv) * scale;
                    const int b = R >> 11, s = R & 2047, h = C >> 6, dh = C & 63;
                    outp[(((long)(b * 16 + h) * 2048 + s) << 6) + dh] = f2bf(val);
                }
            } else {
                // V path: [b][h][dh][s]; rr -> consecutive s -> short4 store
                const int R0 = rowbase + wr + m * 16 + lg * 4;
                const int b = R0 >> 11, s0 = R0 & 2047, h = C >> 6, dh = C & 63;
                short4 o;
                o.x = f2bf(acc[m][n][0] + bv);
                o.y = f2bf(acc[m][n][1] + bv);
                o.z = f2bf(acc[m][n][2] + bv);
                o.w = f2bf(acc[m][n][3] + bv);
                *reinterpret_cast<short4*>(&outp[(((long)(b * 16 + h) * 64 + dh) << 11) + s0]) = o;
            }
        }
    }
}

// ---------------------------------------------------------------------------
// Out-projection GEMM: f32 out = A*WoT + bias + resid. 64x128 tile -> 512
// blocks (2/CU) so staging waits overlap across blocks.
__global__ __launch_bounds__(256) void k_gemm_o(
    const short* __restrict__ A, const short* __restrict__ BT,
    const float* __restrict__ bias, const float* __restrict__ resid,
    float* __restrict__ outp)
{
    __shared__ short As[64 * 64];
    __shared__ short Bs[128 * 64];
    const int tid = threadIdx.x, w = tid >> 6, lane = tid & 63;
    const int lr = lane & 15, lg = lane >> 4;
    const int rowbase = blockIdx.y * 64, colbase = blockIdx.x * 128;
    const int wr = (w >> 1) * 32, wc = (w & 1) * 64;
    const int srow = lane >> 3, sc_ = (lane & 7) ^ srow;

    f32x4 acc[2][4] = {};

    for (int kb = 0; kb < 1024; kb += 64) {
#pragma unroll
        for (int ii = 0; ii < 2; ++ii) {
            const int rl = w * 16 + ii * 8 + srow;
            gll16(A + (long)(rowbase + rl) * 1024 + kb + sc_ * 8, &As[(w * 16 + ii * 8) * 64]);
        }
#pragma unroll
        for (int ii = 0; ii < 4; ++ii) {
            const int rl = w * 32 + ii * 8 + srow;
            gll16(BT + (long)(colbase + rl) * 1024 + kb + sc_ * 8, &Bs[(w * 32 + ii * 8) * 64]);
        }
        __syncthreads();
#pragma unroll
        for (int ks = 0; ks < 2; ++ks) {
            bf16x8 a[2], bq[4];
#pragma unroll
            for (int m = 0; m < 2; ++m) {
                const int r = wr + m * 16 + lr;
                a[m] = *reinterpret_cast<const bf16x8*>(&As[r * 64 + (((ks * 4 + lg) ^ (r & 7)) << 3)]);
            }
#pragma unroll
            for (int n = 0; n < 4; ++n) {
                const int r = wc + n * 16 + lr;
                bq[n] = *reinterpret_cast<const bf16x8*>(&Bs[r * 64 + (((ks * 4 + lg) ^ (r & 7)) << 3)]);
            }
#pragma unroll
            for (int m = 0; m < 2; ++m)
#pragma unroll
                for (int n = 0; n < 4; ++n)
                    acc[m][n] = __builtin_amdgcn_mfma_f32_16x16x32_bf16(a[m], bq[n], acc[m][n], 0, 0, 0);
        }
        __syncthreads();
    }

#pragma unroll
    for (int m = 0; m < 2; ++m) {
#pragma unroll
        for (int n = 0; n < 4; ++n) {
            const int C = colbase + wc + n * 16 + lr;
            const float bv = bias[C];
#pragma unroll
            for (int rr = 0; rr < 4; ++rr) {
                const int R = rowbase + wr + m * 16 + lg * 4 + rr;
                const long idx = (long)R * 1024 + C;
                outp[idx] = acc[m][n][rr] + bv + resid[idx];
            }
        }
    }
}

// ---------------------------------------------------------------------------
// Attention. Both passes: 4-buffer K ring, 2 chunks per barrier; V read
// direct from global (L1/L2-resident per bh) in pass 1.
// Pass 1: QK -> p=exp2(s) -> l+=p -> Ps -> PV (no max tracking).
// Pass 2: QK recompute, p=exp2(s-C) -> coalesced float4 attn stores.
__global__ __launch_bounds__(256, 4) void k_attn(
    const short* __restrict__ qh, const short* __restrict__ kh,
    const short* __restrict__ vt, const unsigned* __restrict__ mbits,
    float* __restrict__ attn_out, short* __restrict__ ctxb)
{
    const int g = blockIdx.x, xcd = g & 7, u = g >> 3;
    const int bh = u >> 2, qt = xcd * 4 + (u & 3);
    const int b = bh >> 4;
    const int tid = threadIdx.x, w = tid >> 6, lane = tid & 63;
    const int lr = lane & 15, lg = lane >> 4;
    const int irow = qt * 64 + w * 16;
    const long arow = (long)bh * 2048 + irow;

    __shared__ short Ks[4][64 * 64];   // 32 KB K ring
    __shared__ short Ps[4][16 * 64];   // 8 KB, XOR-swizzled

    const short* qhp = qh + arow * 64;
    const short* khp = kh + (long)bh * 131072;
    const short* vtp = vt + (long)bh * 131072;
    const unsigned* mbp = mbits + (long)b * 131072 + (long)irow * 64;

    const bf16x8 aq0 = *reinterpret_cast<const bf16x8*>(&qhp[lr * 64 + lg * 8]);
    const bf16x8 aq1 = *reinterpret_cast<const bf16x8*>(&qhp[lr * 64 + 32 + lg * 8]);
    const int srow = lane >> 3, sc_ = (lane & 7) ^ srow;

    auto stage_k = [&](int buf, int ch) {
#pragma unroll
        for (int ii = 0; ii < 2; ++ii) {
            const int r0 = w * 16 + ii * 8;
            gll16(khp + (long)(ch * 64 + r0 + srow) * 64 + sc_ * 8, &Ks[buf][r0 * 64]);
        }
    };
    auto kfrag = [&](int buf, int t, int ks) -> bf16x8 {
        const int r = t * 16 + lr;
        return *reinterpret_cast<const bf16x8*>(&Ks[buf][r * 64 + (((ks * 4 + lg) ^ (r & 7)) << 3)]);
    };
    auto ps_write = [&](int row, int t, float p) {
        const int ch8 = (t * 2 + (lr >> 3)) ^ (row & 7);
        Ps[w][row * 64 + (ch8 << 3) + (lr & 7)] = f2bf(p);
    };

    // =============== pass 1: QK -> exp2 -> l -> PV (V direct) ===============
    float l[4] = {0.f, 0.f, 0.f, 0.f};
    f32x4 acc[4] = {};

    auto do_chunk1 = [&](int ch, unsigned (&mw)[4][2]) {
        const int buf = ch & 3;
#pragma unroll
        for (int t = 0; t < 4; ++t) {
            f32x4 sc = {};
            sc = __builtin_amdgcn_mfma_f32_16x16x32_bf16(aq0, kfrag(buf, t, 0), sc, 0, 0, 0);
            sc = __builtin_amdgcn_mfma_f32_16x16x32_bf16(aq1, kfrag(buf, t, 1), sc, 0, 0, 0);
#pragma unroll
            for (int rr = 0; rr < 4; ++rr) {
                const bool masked = (mw[rr][t >> 1] >> (((t & 1) << 4) + lr)) & 1;
                const float p = exp2f(masked ? -1e9f : sc[rr]);
                l[rr] += p;
                ps_write(lg * 4 + rr, t, p);
            }
        }
        const bf16x8 pa0 = *reinterpret_cast<const bf16x8*>(&Ps[w][lr * 64 + (((0 * 4 + lg) ^ (lr & 7)) << 3)]);
        const bf16x8 pa1 = *reinterpret_cast<const bf16x8*>(&Ps[w][lr * 64 + (((1 * 4 + lg) ^ (lr & 7)) << 3)]);
        const short* vc = vtp + ch * 64;
#pragma unroll
        for (int gi = 0; gi < 4; ++gi) {
            const bf16x8 v0 = *reinterpret_cast<const bf16x8*>(&vc[(long)(gi * 16 + lr) * 2048 + lg * 8]);
            const bf16x8 v1 = *reinterpret_cast<const bf16x8*>(&vc[(long)(gi * 16 + lr) * 2048 + 32 + lg * 8]);
            acc[gi] = __builtin_amdgcn_mfma_f32_16x16x32_bf16(pa0, v0, acc[gi], 0, 0, 0);
            acc[gi] = __builtin_amdgcn_mfma_f32_16x16x32_bf16(pa1, v1, acc[gi], 0, 0, 0);
        }
    };

    stage_k(0, 0); stage_k(1, 1);
    asm volatile("s_waitcnt vmcnt(0)" ::: "memory");
    __builtin_amdgcn_s_barrier();
    asm volatile("" ::: "memory");

    for (int it = 0; it < 16; ++it) {
        const int chA = it * 2, chB = chA + 1;
        unsigned mwA[4][2], mwB[4][2];
#pragma unroll
        for (int rr = 0; rr < 4; ++rr) {
            mwA[rr][0] = mbp[(lg * 4 + rr) * 64 + chA * 2];
            mwA[rr][1] = mbp[(lg * 4 + rr) * 64 + chA * 2 + 1];
            mwB[rr][0] = mbp[(lg * 4 + rr) * 64 + chB * 2];
            mwB[rr][1] = mbp[(lg * 4 + rr) * 64 + chB * 2 + 1];
        }
        asm volatile("" ::: "memory");
        stage_k((chA + 2) & 3, (chA + 2) & 31);
        stage_k((chB + 2) & 3, (chB + 2) & 31);
        asm volatile("" ::: "memory");

        do_chunk1(chA, mwA);
        do_chunk1(chB, mwB);

        // V-load waits have already retired the K-glls (in-order); this is ~free
        asm volatile("s_waitcnt vmcnt(0)" ::: "memory");
        __builtin_amdgcn_s_barrier();
        asm volatile("" ::: "memory");
    }

    // butterfly sum of l; C = log2(l); ctx writeout (normalized)
    float C[4];
#pragma unroll
    for (int rr = 0; rr < 4; ++rr) {
#pragma unroll
        for (int off = 1; off < 16; off <<= 1) l[rr] += __shfl_xor(l[rr], off, 16);
        l[rr] = fmaxf(l[rr], 1e-30f);
        C[rr] = log2f(l[rr]);
    }
#pragma unroll
    for (int gi = 0; gi < 4; ++gi)
#pragma unroll
        for (int rr = 0; rr < 4; ++rr)
            ctxb[(arow + lg * 4 + rr) * 64 + gi * 16 + lr] = f2bf(acc[gi][rr] / l[rr]);

    // =============== pass 2: K ring, 2 chunks per barrier, attn stores =====
    auto emit_chunk = [&](int ch, unsigned (&mw)[4][2]) {
        const int buf = ch & 3;
#pragma unroll
        for (int t = 0; t < 4; ++t) {
            f32x4 sc = {};
            sc = __builtin_amdgcn_mfma_f32_16x16x32_bf16(aq0, kfrag(buf, t, 0), sc, 0, 0, 0);
            sc = __builtin_amdgcn_mfma_f32_16x16x32_bf16(aq1, kfrag(buf, t, 1), sc, 0, 0, 0);
#pragma unroll
            for (int rr = 0; rr < 4; ++rr) {
                const bool masked = (mw[rr][t >> 1] >> (((t & 1) << 4) + lr)) & 1;
                const float p = exp2f((masked ? -1e9f : sc[rr]) - C[rr]);
                ps_write(lg * 4 + rr, t, p);
            }
        }
#pragma unroll
        for (int i2 = 0; i2 < 4; ++i2) {
            const int r = i2 * 4 + lg;
            const short4 p4 = *reinterpret_cast<const short4*>(
                &Ps[w][r * 64 + ((((lr >> 1)) ^ (r & 7)) << 3) + ((lr & 1) << 2)]);
            float4 o;
            o.x = bf2f(p4.x); o.y = bf2f(p4.y); o.z = bf2f(p4.z); o.w = bf2f(p4.w);
            *reinterpret_cast<float4*>(&attn_out[(arow + r) * 2048 + ch * 64 + lr * 4]) = o;
        }
    };

    stage_k(0, 0); stage_k(1, 1);
    asm volatile("s_waitcnt vmcnt(0)" ::: "memory");
    __builtin_amdgcn_s_barrier();
    asm volatile("" ::: "memory");

    for (int it = 0; it < 16; ++it) {
        const int chA = it * 2, chB = chA + 1;
        unsigned mwA[4][2], mwB[4][2];
#pragma unroll
        for (int rr = 0; rr < 4; ++rr) {
            mwA[rr][0] = mbp[(lg * 4 + rr) * 64 + chA * 2];
            mwA[rr][1] = mbp[(lg * 4 + rr) * 64 + chA * 2 + 1];
            mwB[rr][0] = mbp[(lg * 4 + rr) * 64 + chB * 2];
            mwB[rr][1] = mbp[(lg * 4 + rr) * 64 + chB * 2 + 1];
        }
        asm volatile("" ::: "memory");
        stage_k((chA + 2) & 3, (chA + 2) & 31);
        stage_k((chB + 2) & 3, (chB + 2) & 31);
        asm volatile("" ::: "memory");

        emit_chunk(chA, mwA);
        emit_chunk(chB, mwB);

        // retire the 4 staged glls (aged a full iteration); keep 8 stores in flight
        asm volatile("s_waitcnt vmcnt(8)" ::: "memory");
        __builtin_amdgcn_s_barrier();
        asm volatile("" ::: "memory");
    }
}

// ---------------------------------------------------------------------------
__global__ __launch_bounds__(256) void k_ln(const float* __restrict__ x,
    const float* __restrict__ gamma, const float* __restrict__ beta,
    float* __restrict__ out)
{
    __shared__ float red[8];
    const int r = blockIdx.x, tid = threadIdx.x;
    const float4 v = reinterpret_cast<const float4*>(x + (long)r * 1024)[tid];
    float s = v.x + v.y + v.z + v.w;
    float q2 = v.x * v.x + v.y * v.y + v.z * v.z + v.w * v.w;
#pragma unroll
    for (int off = 32; off; off >>= 1) {
        s += __shfl_xor(s, off, 64);
        q2 += __shfl_xor(q2, off, 64);
    }
    if ((tid & 63) == 0) { red[(tid >> 6) * 2] = s; red[(tid >> 6) * 2 + 1] = q2; }
    __syncthreads();
    s = red[0] + red[2] + red[4] + red[6];
    q2 = red[1] + red[3] + red[5] + red[7];
    const float mu = s * (1.0f / 1024.0f);
    const float var = q2 * (1.0f / 1024.0f) - mu * mu;
    const float rs = rsqrtf(var + 1e-5f);
    const float4 gm = reinterpret_cast<const float4*>(gamma)[tid];
    const float4 bb = reinterpret_cast<const float4*>(beta)[tid];
    float4 o;
    o.x = (v.x - mu) * rs * gm.x + bb.x;
    o.y = (v.y - mu) * rs * gm.y + bb.y;
    o.z = (v.z - mu) * rs * gm.z + bb.z;
    o.w = (v.w - mu) * rs * gm.w + bb.w;
    reinterpret_cast<float4*>(out + (long)r * 1024)[tid] = o;
}

// ---------------------------------------------------------------------------
extern "C" void kernel_launch(void* const* d_in, const int* in_sizes, int n_in,
                              void* d_out, int out_size, void* d_ws, size_t ws_size,
                              hipStream_t stream)
{
    const float* qin  = (const float*)d_in[0];
    const float* kin  = (const float*)d_in[1];
    const float* vin  = (const float*)d_in[2];
    const int*   mask = (const int*)d_in[3];
    const float* Wq = (const float*)d_in[4];
    const float* bq = (const float*)d_in[5];
    const float* Wk = (const float*)d_in[6];
    const float* bk = (const float*)d_in[7];
    const float* Wv = (const float*)d_in[8];
    const float* bv = (const float*)d_in[9];
    const float* Wo = (const float*)d_in[10];
    const float* bo = (const float*)d_in[11];
    const float* gamma = (const float*)d_in[12];
    const float* beta  = (const float*)d_in[13];

    char* ws = (char*)d_ws;
    short* WqT = (short*)(ws + (0ul  << 20));
    short* WkT = (short*)(ws + (2ul  << 20));
    short* WvT = (short*)(ws + (4ul  << 20));
    short* WoT = (short*)(ws + (6ul  << 20));
    short* qbf = (short*)(ws + (8ul  << 20));   // dead after projections; reused by xb
    short* kbf = (short*)(ws + (16ul << 20));   // dead after projections; reused by xb
    short* vbf = (short*)(ws + (24ul << 20));
    short* qh  = (short*)(ws + (32ul << 20));
    short* khb = (short*)(ws + (40ul << 20));
    short* vtb = (short*)(ws + (48ul << 20));
    unsigned* mb = (unsigned*)(ws + (56ul << 20));
    short* ctxb = (short*)(ws + (57ul << 20));  // 8 MB
    float* xb   = (float*)(ws + (8ul  << 20));  // 16 MB, overlaps dead qbf/kbf

    float* outLN = (float*)d_out;
    float* attnO = (float*)d_out + 4194304;

    const dim3 blk(256);
    k_prep<<<dim3(11264), blk, 0, stream>>>(qin, kin, vin, qbf, kbf, vbf,
                                            Wq, Wk, Wv, Wo, WqT, WkT, WvT, WoT, mask, mb);
    k_gemm_qkv<<<dim3(8, 32, 3), blk, 0, stream>>>(qbf, kbf, vbf, WqT, WkT, WvT,
                                                   bq, bk, bv, qh, khb, vtb);
    k_attn<<<dim3(1024), blk, 0, stream>>>(qh, khb, vtb, mb, attnO, ctxb);
    k_gemm_o<<<dim3(8, 64), blk, 0, stream>>>(ctxb, WoT, bo, qin, xb);
    k_ln<<<dim3(4096), blk, 0, stream>>>(xb, gamma, beta, outLN);
}

// Round 12
// 305.427 us; speedup vs baseline: 1.1990x; 1.1990x over previous
//
#include <hip/hip_runtime.h>
#include <hip/hip_bf16.h>

typedef __attribute__((ext_vector_type(8))) short bf16x8;
typedef __attribute__((ext_vector_type(4))) float f32x4;

__device__ __forceinline__ short f2bf(float f) {
    union { float f; unsigned u; } v; v.f = f;
    unsigned r = (v.u + 0x7FFFu + ((v.u >> 16) & 1u)) >> 16;
    return (short)r;
}
__device__ __forceinline__ float bf2f(short s) {
    union { unsigned u; float f; } v; v.u = ((unsigned)(unsigned short)s) << 16;
    return v.f;
}
__device__ __forceinline__ void gll16(const void* g, void* l) {
    __builtin_amdgcn_global_load_lds(
        (const __attribute__((address_space(1))) unsigned int*)g,
        (__attribute__((address_space(3))) unsigned int*)l, 16, 0, 0);
}

// Q projection pre-scaled by 0.125 * log2(e): softmax runs in exp2 domain.
#define QSCALE 0.18033688011112042f

// ---------------------------------------------------------------------------
// Fused prep: [0,6144) f32->bf16 cvt of q,k,v ; [6144,10240) weight transpose
// +cvt ; [10240,11264) mask bit-pack.
__global__ __launch_bounds__(256) void k_prep(
    const float* __restrict__ qin, const float* __restrict__ kin, const float* __restrict__ vin,
    short* __restrict__ qbf, short* __restrict__ kbf, short* __restrict__ vbf,
    const float* __restrict__ Wq, const float* __restrict__ Wk,
    const float* __restrict__ Wv, const float* __restrict__ Wo,
    short* __restrict__ WqT, short* __restrict__ WkT,
    short* __restrict__ WvT, short* __restrict__ WoT,
    const int* __restrict__ mask, unsigned* __restrict__ mb)
{
    __shared__ int sm[8192];
    const int bid = blockIdx.x, tid = threadIdx.x;
    if (bid < 6144) {
        const float* in = bid < 2048 ? qin : (bid < 4096 ? kin : vin);
        short* out = bid < 2048 ? qbf : (bid < 4096 ? kbf : vbf);
        const long i = ((long)(bid & 2047) * 256 + tid) * 8;
        float4 f0 = *reinterpret_cast<const float4*>(&in[i]);
        float4 f1 = *reinterpret_cast<const float4*>(&in[i + 4]);
        bf16x8 v;
        v[0] = f2bf(f0.x); v[1] = f2bf(f0.y); v[2] = f2bf(f0.z); v[3] = f2bf(f0.w);
        v[4] = f2bf(f1.x); v[5] = f2bf(f1.y); v[6] = f2bf(f1.z); v[7] = f2bf(f1.w);
        *reinterpret_cast<bf16x8*>(&out[i]) = v;
    } else if (bid < 10240) {
        const int t2 = bid - 6144, which = t2 >> 10, local = t2 & 1023;
        const float* W = which == 0 ? Wq : (which == 1 ? Wk : (which == 2 ? Wv : Wo));
        short* WT = which == 0 ? WqT : (which == 1 ? WkT : (which == 2 ? WvT : WoT));
        float (*t)[33] = reinterpret_cast<float(*)[33]>(sm);
        const int rb = (local >> 5) * 32, cb = (local & 31) * 32;
        const int tr = tid >> 3, tc = (tid & 7) * 4;
        const float4 v = *reinterpret_cast<const float4*>(&W[(long)(rb + tr) * 1024 + cb + tc]);
        t[tr][tc + 0] = v.x; t[tr][tc + 1] = v.y; t[tr][tc + 2] = v.z; t[tr][tc + 3] = v.w;
        __syncthreads();
        short4 o;
        o.x = f2bf(t[tc + 0][tr]); o.y = f2bf(t[tc + 1][tr]);
        o.z = f2bf(t[tc + 2][tr]); o.w = f2bf(t[tc + 3][tr]);
        *reinterpret_cast<short4*>(&WT[(long)(cb + tr) * 1024 + rb + tc]) = o;
    } else {
        const long base = (long)(bid - 10240) * 8192;
#pragma unroll
        for (int i = 0; i < 8; ++i)
            *reinterpret_cast<int4*>(&sm[i * 1024 + tid * 4]) =
                *reinterpret_cast<const int4*>(&mask[base + i * 1024 + tid * 4]);
        __syncthreads();
        unsigned wv = 0;
#pragma unroll
        for (int j = 0; j < 32; ++j) wv |= (sm[tid * 32 + j] != 0 ? 1u : 0u) << j;
        mb[base / 32 + tid] = wv;
    }
}

// ---------------------------------------------------------------------------
// Fused QKV projection GEMM (z = 0:Q, 1:K, 2:V). 128x128 tile, BK=64, gll.
__global__ __launch_bounds__(256) void k_gemm_qkv(
    const short* __restrict__ A0, const short* __restrict__ A1, const short* __restrict__ A2,
    const short* __restrict__ B0, const short* __restrict__ B1, const short* __restrict__ B2,
    const float* __restrict__ b0, const float* __restrict__ b1, const float* __restrict__ b2,
    short* __restrict__ o0, short* __restrict__ o1, short* __restrict__ o2)
{
    __shared__ short As[128 * 64];
    __shared__ short Bs[128 * 64];
    const int z = blockIdx.z;
    const short* A = z == 0 ? A0 : (z == 1 ? A1 : A2);
    const short* BT = z == 0 ? B0 : (z == 1 ? B1 : B2);
    const float* bias = z == 0 ? b0 : (z == 1 ? b1 : b2);
    short* outp = z == 0 ? o0 : (z == 1 ? o1 : o2);
    const float scale = z == 0 ? QSCALE : 1.0f;

    const int tid = threadIdx.x, w = tid >> 6, lane = tid & 63;
    const int lr = lane & 15, lg = lane >> 4;
    const int rowbase = blockIdx.y * 128, colbase = blockIdx.x * 128;
    const int wr = (w >> 1) * 64, wc = (w & 1) * 64;
    const int srow = lane >> 3, sc_ = (lane & 7) ^ srow;

    f32x4 acc[4][4] = {};

    for (int kb = 0; kb < 1024; kb += 64) {
#pragma unroll
        for (int ii = 0; ii < 4; ++ii) {
            const int rl = w * 32 + ii * 8 + srow;
            gll16(A + (long)(rowbase + rl) * 1024 + kb + sc_ * 8, &As[(w * 32 + ii * 8) * 64]);
            gll16(BT + (long)(colbase + rl) * 1024 + kb + sc_ * 8, &Bs[(w * 32 + ii * 8) * 64]);
        }
        __syncthreads();
#pragma unroll
        for (int ks = 0; ks < 2; ++ks) {
            bf16x8 a[4], bq[4];
#pragma unroll
            for (int m = 0; m < 4; ++m) {
                const int r = wr + m * 16 + lr;
                a[m] = *reinterpret_cast<const bf16x8*>(&As[r * 64 + (((ks * 4 + lg) ^ (r & 7)) << 3)]);
            }
#pragma unroll
            for (int n = 0; n < 4; ++n) {
                const int r = wc + n * 16 + lr;
                bq[n] = *reinterpret_cast<const bf16x8*>(&Bs[r * 64 + (((ks * 4 + lg) ^ (r & 7)) << 3)]);
            }
#pragma unroll
            for (int m = 0; m < 4; ++m)
#pragma unroll
                for (int n = 0; n < 4; ++n)
                    acc[m][n] = __builtin_amdgcn_mfma_f32_16x16x32_bf16(a[m], bq[n], acc[m][n], 0, 0, 0);
        }
        __syncthreads();
    }

#pragma unroll
    for (int m = 0; m < 4; ++m) {
#pragma unroll
        for (int n = 0; n < 4; ++n) {
            const int C = colbase + wc + n * 16 + lr;
            const float bv = bias[C];
            if (z != 2) {
#pragma unroll
                for (int rr = 0; rr < 4; ++rr) {
                    const int R = rowbase + wr + m * 16 + lg * 4 + rr;
                    const float val = (acc[m][n][rr] + bv) * scale;
                    const int b = R >> 11, s = R & 2047, h = C >> 6, dh = C & 63;
                    outp[(((long)(b * 16 + h) * 2048 + s) << 6) + dh] = f2bf(val);
                }
            } else {
                // V path: [b][h][dh][s]; rr -> consecutive s -> short4 store
                const int R0 = rowbase + wr + m * 16 + lg * 4;
                const int b = R0 >> 11, s0 = R0 & 2047, h = C >> 6, dh = C & 63;
                short4 o;
                o.x = f2bf(acc[m][n][0] + bv);
                o.y = f2bf(acc[m][n][1] + bv);
                o.z = f2bf(acc[m][n][2] + bv);
                o.w = f2bf(acc[m][n][3] + bv);
                *reinterpret_cast<short4*>(&outp[(((long)(b * 16 + h) * 64 + dh) << 11) + s0]) = o;
            }
        }
    }
}

// ---------------------------------------------------------------------------
// Out-projection GEMM: f32 out = A*WoT + bias + resid. 64x128 tile -> 512
// blocks (2/CU) so staging waits overlap across blocks.
__global__ __launch_bounds__(256) void k_gemm_o(
    const short* __restrict__ A, const short* __restrict__ BT,
    const float* __restrict__ bias, const float* __restrict__ resid,
    float* __restrict__ outp)
{
    __shared__ short As[64 * 64];
    __shared__ short Bs[128 * 64];
    const int tid = threadIdx.x, w = tid >> 6, lane = tid & 63;
    const int lr = lane & 15, lg = lane >> 4;
    const int rowbase = blockIdx.y * 64, colbase = blockIdx.x * 128;
    const int wr = (w >> 1) * 32, wc = (w & 1) * 64;
    const int srow = lane >> 3, sc_ = (lane & 7) ^ srow;

    f32x4 acc[2][4] = {};

    for (int kb = 0; kb < 1024; kb += 64) {
#pragma unroll
        for (int ii = 0; ii < 2; ++ii) {
            const int rl = w * 16 + ii * 8 + srow;
            gll16(A + (long)(rowbase + rl) * 1024 + kb + sc_ * 8, &As[(w * 16 + ii * 8) * 64]);
        }
#pragma unroll
        for (int ii = 0; ii < 4; ++ii) {
            const int rl = w * 32 + ii * 8 + srow;
            gll16(BT + (long)(colbase + rl) * 1024 + kb + sc_ * 8, &Bs[(w * 32 + ii * 8) * 64]);
        }
        __syncthreads();
#pragma unroll
        for (int ks = 0; ks < 2; ++ks) {
            bf16x8 a[2], bq[4];
#pragma unroll
            for (int m = 0; m < 2; ++m) {
                const int r = wr + m * 16 + lr;
                a[m] = *reinterpret_cast<const bf16x8*>(&As[r * 64 + (((ks * 4 + lg) ^ (r & 7)) << 3)]);
            }
#pragma unroll
            for (int n = 0; n < 4; ++n) {
                const int r = wc + n * 16 + lr;
                bq[n] = *reinterpret_cast<const bf16x8*>(&Bs[r * 64 + (((ks * 4 + lg) ^ (r & 7)) << 3)]);
            }
#pragma unroll
            for (int m = 0; m < 2; ++m)
#pragma unroll
                for (int n = 0; n < 4; ++n)
                    acc[m][n] = __builtin_amdgcn_mfma_f32_16x16x32_bf16(a[m], bq[n], acc[m][n], 0, 0, 0);
        }
        __syncthreads();
    }

#pragma unroll
    for (int m = 0; m < 2; ++m) {
#pragma unroll
        for (int n = 0; n < 4; ++n) {
            const int C = colbase + wc + n * 16 + lr;
            const float bv = bias[C];
#pragma unroll
            for (int rr = 0; rr < 4; ++rr) {
                const int R = rowbase + wr + m * 16 + lg * 4 + rr;
                const long idx = (long)R * 1024 + C;
                outp[idx] = acc[m][n][rr] + bv + resid[idx];
            }
        }
    }
}

// ---------------------------------------------------------------------------
// Attention (r10 proven version). Pass 1: dbuf K+V in LDS, QK -> exp2 -> l
// -> Ps -> PV, per-chunk barrier. Pass 2: 4-buffer K ring, 2 chunks per
// barrier, vmcnt(8) keeps 8 attn stores in flight.
__global__ __launch_bounds__(256, 4) void k_attn(
    const short* __restrict__ qh, const short* __restrict__ kh,
    const short* __restrict__ vt, const unsigned* __restrict__ mbits,
    float* __restrict__ attn_out, short* __restrict__ ctxb)
{
    const int g = blockIdx.x, xcd = g & 7, u = g >> 3;
    const int bh = u >> 2, qt = xcd * 4 + (u & 3);
    const int b = bh >> 4;
    const int tid = threadIdx.x, w = tid >> 6, lane = tid & 63;
    const int lr = lane & 15, lg = lane >> 4;
    const int irow = qt * 64 + w * 16;
    const long arow = (long)bh * 2048 + irow;

    __shared__ short KV[4][64 * 64];   // 32 KB: pass1 K=KV[0..1], V=KV[2..3]; pass2 K-ring
    __shared__ short Ps[4][16 * 64];   // 8 KB, XOR-swizzled

    const short* qhp = qh + arow * 64;
    const short* khp = kh + (long)bh * 131072;
    const short* vtp = vt + (long)bh * 131072;
    const unsigned* mbp = mbits + (long)b * 131072 + (long)irow * 64;

    const bf16x8 aq0 = *reinterpret_cast<const bf16x8*>(&qhp[lr * 64 + lg * 8]);
    const bf16x8 aq1 = *reinterpret_cast<const bf16x8*>(&qhp[lr * 64 + 32 + lg * 8]);
    const int srow = lane >> 3, sc_ = (lane & 7) ^ srow;

    auto stage_k = [&](int buf, int ch) {
#pragma unroll
        for (int ii = 0; ii < 2; ++ii) {
            const int r0 = w * 16 + ii * 8;
            gll16(khp + (long)(ch * 64 + r0 + srow) * 64 + sc_ * 8, &KV[buf][r0 * 64]);
        }
    };
    auto stage_v = [&](int buf, int ch) {
#pragma unroll
        for (int ii = 0; ii < 2; ++ii) {
            const int r0 = w * 16 + ii * 8;
            gll16(vtp + (long)(r0 + srow) * 2048 + ch * 64 + sc_ * 8, &KV[2 + buf][r0 * 64]);
        }
    };
    auto kfrag = [&](int buf, int t, int ks) -> bf16x8 {
        const int r = t * 16 + lr;
        return *reinterpret_cast<const bf16x8*>(&KV[buf][r * 64 + (((ks * 4 + lg) ^ (r & 7)) << 3)]);
    };
    auto vfrag = [&](int buf, int gi, int ks) -> bf16x8 {
        const int r = gi * 16 + lr;
        return *reinterpret_cast<const bf16x8*>(&KV[2 + buf][r * 64 + (((ks * 4 + lg) ^ (r & 7)) << 3)]);
    };
    auto ps_write = [&](int row, int t, float p) {
        const int ch8 = (t * 2 + (lr >> 3)) ^ (row & 7);
        Ps[w][row * 64 + (ch8 << 3) + (lr & 7)] = f2bf(p);
    };

    // =============== pass 1: QK -> exp2 -> l -> PV (no max) ===============
    float l[4] = {0.f, 0.f, 0.f, 0.f};
    f32x4 acc[4] = {};

    stage_k(0, 0); stage_v(0, 0);
    asm volatile("s_waitcnt vmcnt(0)" ::: "memory");
    __builtin_amdgcn_s_barrier();
    asm volatile("" ::: "memory");

    for (int ch = 0; ch < 32; ++ch) {
        const int cur = ch & 1;
        unsigned mw[4][2];
#pragma unroll
        for (int rr = 0; rr < 4; ++rr) {
            mw[rr][0] = mbp[(lg * 4 + rr) * 64 + ch * 2];
            mw[rr][1] = mbp[(lg * 4 + rr) * 64 + ch * 2 + 1];
        }
        asm volatile("" ::: "memory");
        if (ch < 31) { stage_k(cur ^ 1, ch + 1); stage_v(cur ^ 1, ch + 1); }
        asm volatile("" ::: "memory");

#pragma unroll
        for (int t = 0; t < 4; ++t) {
            f32x4 sc = {};
            sc = __builtin_amdgcn_mfma_f32_16x16x32_bf16(aq0, kfrag(cur, t, 0), sc, 0, 0, 0);
            sc = __builtin_amdgcn_mfma_f32_16x16x32_bf16(aq1, kfrag(cur, t, 1), sc, 0, 0, 0);
#pragma unroll
            for (int rr = 0; rr < 4; ++rr) {
                const bool masked = (mw[rr][t >> 1] >> (((t & 1) << 4) + lr)) & 1;
                const float p = exp2f(masked ? -1e9f : sc[rr]);
                l[rr] += p;
                ps_write(lg * 4 + rr, t, p);
            }
        }
        const bf16x8 pa0 = *reinterpret_cast<const bf16x8*>(&Ps[w][lr * 64 + (((0 * 4 + lg) ^ (lr & 7)) << 3)]);
        const bf16x8 pa1 = *reinterpret_cast<const bf16x8*>(&Ps[w][lr * 64 + (((1 * 4 + lg) ^ (lr & 7)) << 3)]);
#pragma unroll
        for (int gi = 0; gi < 4; ++gi) {
            acc[gi] = __builtin_amdgcn_mfma_f32_16x16x32_bf16(pa0, vfrag(cur, gi, 0), acc[gi], 0, 0, 0);
            acc[gi] = __builtin_amdgcn_mfma_f32_16x16x32_bf16(pa1, vfrag(cur, gi, 1), acc[gi], 0, 0, 0);
        }
        asm volatile("s_waitcnt vmcnt(0)" ::: "memory");
        __builtin_amdgcn_s_barrier();
        asm volatile("" ::: "memory");
    }

    // butterfly sum of l; C = log2(l); ctx writeout (normalized)
    float C[4];
#pragma unroll
    for (int rr = 0; rr < 4; ++rr) {
#pragma unroll
        for (int off = 1; off < 16; off <<= 1) l[rr] += __shfl_xor(l[rr], off, 16);
        l[rr] = fmaxf(l[rr], 1e-30f);
        C[rr] = log2f(l[rr]);
    }
#pragma unroll
    for (int gi = 0; gi < 4; ++gi)
#pragma unroll
        for (int rr = 0; rr < 4; ++rr)
            ctxb[(arow + lg * 4 + rr) * 64 + gi * 16 + lr] = f2bf(acc[gi][rr] / l[rr]);

    // =============== pass 2: 4-buffer K ring, 2 chunks per barrier =========
    auto emit_chunk = [&](int ch, unsigned (&mw)[4][2]) {
        const int buf = ch & 3;
#pragma unroll
        for (int t = 0; t < 4; ++t) {
            f32x4 sc = {};
            sc = __builtin_amdgcn_mfma_f32_16x16x32_bf16(aq0, kfrag(buf, t, 0), sc, 0, 0, 0);
            sc = __builtin_amdgcn_mfma_f32_16x16x32_bf16(aq1, kfrag(buf, t, 1), sc, 0, 0, 0);
#pragma unroll
            for (int rr = 0; rr < 4; ++rr) {
                const bool masked = (mw[rr][t >> 1] >> (((t & 1) << 4) + lr)) & 1;
                const float p = exp2f((masked ? -1e9f : sc[rr]) - C[rr]);
                ps_write(lg * 4 + rr, t, p);
            }
        }
#pragma unroll
        for (int i2 = 0; i2 < 4; ++i2) {
            const int r = i2 * 4 + lg;
            const short4 p4 = *reinterpret_cast<const short4*>(
                &Ps[w][r * 64 + ((((lr >> 1)) ^ (r & 7)) << 3) + ((lr & 1) << 2)]);
            float4 o;
            o.x = bf2f(p4.x); o.y = bf2f(p4.y); o.z = bf2f(p4.z); o.w = bf2f(p4.w);
            *reinterpret_cast<float4*>(&attn_out[(arow + r) * 2048 + ch * 64 + lr * 4]) = o;
        }
    };

    stage_k(0, 0); stage_k(1, 1);
    asm volatile("s_waitcnt vmcnt(0)" ::: "memory");
    __builtin_amdgcn_s_barrier();
    asm volatile("" ::: "memory");

    for (int it = 0; it < 16; ++it) {
        const int chA = it * 2, chB = chA + 1;
        unsigned mwA[4][2], mwB[4][2];
#pragma unroll
        for (int rr = 0; rr < 4; ++rr) {
            mwA[rr][0] = mbp[(lg * 4 + rr) * 64 + chA * 2];
            mwA[rr][1] = mbp[(lg * 4 + rr) * 64 + chA * 2 + 1];
            mwB[rr][0] = mbp[(lg * 4 + rr) * 64 + chB * 2];
            mwB[rr][1] = mbp[(lg * 4 + rr) * 64 + chB * 2 + 1];
        }
        asm volatile("" ::: "memory");
        // stage next pair (mod-wrapped on last iter; lands in dead buffers)
        stage_k((chA + 2) & 3, (chA + 2) & 31);
        stage_k((chB + 2) & 3, (chB + 2) & 31);
        asm volatile("" ::: "memory");

        emit_chunk(chA, mwA);
        emit_chunk(chB, mwB);

        // retire the 4 staged glls (aged a full iteration); keep 8 stores in flight
        asm volatile("s_waitcnt vmcnt(8)" ::: "memory");
        __builtin_amdgcn_s_barrier();
        asm volatile("" ::: "memory");
    }
}

// ---------------------------------------------------------------------------
__global__ __launch_bounds__(256) void k_ln(const float* __restrict__ x,
    const float* __restrict__ gamma, const float* __restrict__ beta,
    float* __restrict__ out)
{
    __shared__ float red[8];
    const int r = blockIdx.x, tid = threadIdx.x;
    const float4 v = reinterpret_cast<const float4*>(x + (long)r * 1024)[tid];
    float s = v.x + v.y + v.z + v.w;
    float q2 = v.x * v.x + v.y * v.y + v.z * v.z + v.w * v.w;
#pragma unroll
    for (int off = 32; off; off >>= 1) {
        s += __shfl_xor(s, off, 64);
        q2 += __shfl_xor(q2, off, 64);
    }
    if ((tid & 63) == 0) { red[(tid >> 6) * 2] = s; red[(tid >> 6) * 2 + 1] = q2; }
    __syncthreads();
    s = red[0] + red[2] + red[4] + red[6];
    q2 = red[1] + red[3] + red[5] + red[7];
    const float mu = s * (1.0f / 1024.0f);
    const float var = q2 * (1.0f / 1024.0f) - mu * mu;
    const float rs = rsqrtf(var + 1e-5f);
    const float4 gm = reinterpret_cast<const float4*>(gamma)[tid];
    const float4 bb = reinterpret_cast<const float4*>(beta)[tid];
    float4 o;
    o.x = (v.x - mu) * rs * gm.x + bb.x;
    o.y = (v.y - mu) * rs * gm.y + bb.y;
    o.z = (v.z - mu) * rs * gm.z + bb.z;
    o.w = (v.w - mu) * rs * gm.w + bb.w;
    reinterpret_cast<float4*>(out + (long)r * 1024)[tid] = o;
}

// ---------------------------------------------------------------------------
extern "C" void kernel_launch(void* const* d_in, const int* in_sizes, int n_in,
                              void* d_out, int out_size, void* d_ws, size_t ws_size,
                              hipStream_t stream)
{
    const float* qin  = (const float*)d_in[0];
    const float* kin  = (const float*)d_in[1];
    const float* vin  = (const float*)d_in[2];
    const int*   mask = (const int*)d_in[3];
    const float* Wq = (const float*)d_in[4];
    const float* bq = (const float*)d_in[5];
    const float* Wk = (const float*)d_in[6];
    const float* bk = (const float*)d_in[7];
    const float* Wv = (const float*)d_in[8];
    const float* bv = (const float*)d_in[9];
    const float* Wo = (const float*)d_in[10];
    const float* bo = (const float*)d_in[11];
    const float* gamma = (const float*)d_in[12];
    const float* beta  = (const float*)d_in[13];

    char* ws = (char*)d_ws;
    short* WqT = (short*)(ws + (0ul  << 20));
    short* WkT = (short*)(ws + (2ul  << 20));
    short* WvT = (short*)(ws + (4ul  << 20));
    short* WoT = (short*)(ws + (6ul  << 20));
    short* qbf = (short*)(ws + (8ul  << 20));   // dead after projections; reused by xb
    short* kbf = (short*)(ws + (16ul << 20));   // dead after projections; reused by xb
    short* vbf = (short*)(ws + (24ul << 20));
    short* qh  = (short*)(ws + (32ul << 20));
    short* khb = (short*)(ws + (40ul << 20));
    short* vtb = (short*)(ws + (48ul << 20));
    unsigned* mb = (unsigned*)(ws + (56ul << 20));
    short* ctxb = (short*)(ws + (57ul << 20));  // 8 MB
    float* xb   = (float*)(ws + (8ul  << 20));  // 16 MB, overlaps dead qbf/kbf

    float* outLN = (float*)d_out;
    float* attnO = (float*)d_out + 4194304;

    const dim3 blk(256);
    k_prep<<<dim3(11264), blk, 0, stream>>>(qin, kin, vin, qbf, kbf, vbf,
                                            Wq, Wk, Wv, Wo, WqT, WkT, WvT, WoT, mask, mb);
    k_gemm_qkv<<<dim3(8, 32, 3), blk, 0, stream>>>(qbf, kbf, vbf, WqT, WkT, WvT,
                                                   bq, bk, bv, qh, khb, vtb);
    k_attn<<<dim3(1024), blk, 0, stream>>>(qh, khb, vtb, mb, attnO, ctxb);
    k_gemm_o<<<dim3(8, 64), blk, 0, stream>>>(ctxb, WoT, bo, qin, xb);
    k_ln<<<dim3(4096), blk, 0, stream>>>(xb, gamma, beta, outLN);
}